// Round 2
// baseline (318.342 us; speedup 1.0000x reference)
//
#include <hip/hip_runtime.h>
#include <stdint.h>

// out = x @ tanh(block_diag(blocks)) -- 16 blocks of 256x256. ALL BUFFERS FLOAT32.
// Kernel 1: pack tanh'd diagonal blocks transposed -> bf16 wsT[j][n][k] (2 MB in d_ws).
// Kernel 2: per (mtile, j): 64x256 MFMA GEMM, A staged f32->bf16, B via global_load_lds.

typedef float floatx4 __attribute__((ext_vector_type(4)));
typedef __bf16 bf16x8 __attribute__((ext_vector_type(8)));

#define LDX 4096
#define NBLK 16
#define BS 256
#define BM 64
#define BN 256
#define BK 32

__device__ __forceinline__ unsigned int f2bf(float f) {
  union { float f; unsigned int i; } x;
  x.f = f;
  unsigned int r = x.i + 0x7FFFu + ((x.i >> 16) & 1u);  // RNE
  return r >> 16;
}

// async global->LDS, 16B/lane. LDS dest = wave-uniform base + lane*16 in lane order.
__device__ __forceinline__ void async_copy16(const void* g, void* l) {
  __builtin_amdgcn_global_load_lds(
      (__attribute__((address_space(1))) void*)(uintptr_t)g,
      (__attribute__((address_space(3))) void*)(unsigned int)(uintptr_t)l,
      16, 0, 0);
}

// wsT[j*65536 + n*256 + k] = tanh(blocks[(j*256+k)*4096 + j*256 + n]), stored bf16.
__global__ __launch_bounds__(256) void tanh_pack(const float* __restrict__ blocks,
                                                 unsigned short* __restrict__ wsT) {
  __shared__ float tile[64][65];  // [k][n], +1 pad for conflict-free column reads
  const int t = threadIdx.x;
  const int tc = blockIdx.x, tr = blockIdx.y, j = blockIdx.z;
  const float* src = blocks + (size_t)(j * BS + tr * 64) * LDX + j * BS + tc * 64;
#pragma unroll
  for (int it = 0; it < 8; ++it) {
    int v = it * 256 + t;
    int row = v >> 5;       // k within tile, 0..63
    int c2 = (v & 31) * 2;  // n within tile, even
    float2 f = *(const float2*)(src + (size_t)row * LDX + c2);
    tile[row][c2] = tanhf(f.x);
    tile[row][c2 + 1] = tanhf(f.y);
  }
  __syncthreads();
  unsigned short* dst = wsT + (size_t)j * BS * BS + (size_t)(tc * 64) * BS + tr * 64;
#pragma unroll
  for (int it = 0; it < 8; ++it) {
    int v = it * 256 + t;
    int nn = v >> 5;        // n within tile
    int k2 = (v & 31) * 2;  // k within tile, even
    unsigned int pair = f2bf(tile[k2][nn]) | (f2bf(tile[k2 + 1][nn]) << 16);
    *(unsigned int*)(dst + (size_t)nn * BS + k2) = pair;  // coalesced dword stores
  }
}

// FUSED=false: B from pre-packed bf16 wsT (global_load_lds).
// FUSED=true : fallback, B from raw f32 blocks with inline tanh (ws too small).
template <int BSTR, bool FUSED>
__global__ __launch_bounds__(256) void bdgemm(const float* __restrict__ x,
                                              const void* __restrict__ bsrc,
                                              float* __restrict__ out) {
  __shared__ unsigned short As[BM * BK];   // [m][k] bf16, k contiguous (stride BK)
  __shared__ unsigned short Bs[BN * BSTR]; // [n][k] bf16, k contiguous (stride BSTR)
  const int t = threadIdx.x;
  const int lane = t & 63;
  const int wave = t >> 6;
  const int mtile = blockIdx.x;  // 0..127
  const int j = blockIdx.y;      // 0..15
  const int m0 = mtile * BM;

  const float* xg = x + (size_t)m0 * LDX + j * BS;

  const int srow = t >> 2;         // staging A: row 0..63
  const int scol = (t & 3) * 8;    // staging A: k-offset {0,8,16,24}
  const int wn = wave * 64;        // wave n-offset (1x4 wave grid, each 64m x 64n)
  const int fr = lane & 15;        // fragment m / n index
  const int fq = (lane >> 4) * 8;  // fragment k base

  floatx4 acc[4][4];
#pragma unroll
  for (int a = 0; a < 4; ++a)
#pragma unroll
    for (int b = 0; b < 4; ++b) acc[a][b] = (floatx4){0.f, 0.f, 0.f, 0.f};

  for (int kt = 0; kt < 8; ++kt) {
    const int k0 = kt * BK;
    // ---- stage A: 64x32 f32 -> bf16, 8 elems/thread ----
    const float* ap = xg + (size_t)srow * LDX + k0 + scol;
    float4 a0 = *(const float4*)(ap);
    float4 a1 = *(const float4*)(ap + 4);
    uint4 pk;
    pk.x = f2bf(a0.x) | (f2bf(a0.y) << 16);
    pk.y = f2bf(a0.z) | (f2bf(a0.w) << 16);
    pk.z = f2bf(a1.x) | (f2bf(a1.y) << 16);
    pk.w = f2bf(a1.z) | (f2bf(a1.w) << 16);
    *(uint4*)(As + t * 8) = pk;  // As[srow*32 + scol], 16B aligned

    // ---- stage B: 256x32 bf16 ----
    if constexpr (!FUSED) {
      const unsigned short* wsb =
          (const unsigned short*)bsrc + (size_t)j * BS * BS;
#pragma unroll
      for (int i = 0; i < 4; ++i) {
        const int n = i * 64 + (t >> 2);  // 0..255
        async_copy16(wsb + (size_t)n * BS + k0 + scol, Bs + i * 2048 + t * 8);
      }
    } else {
      const float* bg = (const float*)bsrc;
#pragma unroll
      for (int i = 0; i < 32; ++i) {
        const int idx = i * 256 + t;
        const int kk = idx >> 8;   // 0..31
        const int nn = idx & 255;  // fast dim: coalesced global read
        float v = tanhf(bg[(size_t)(j * BS + k0 + kk) * LDX + j * BS + nn]);
        Bs[nn * BSTR + kk] = (unsigned short)f2bf(v);
      }
    }
    __syncthreads();

    bf16x8 af[4], bfm[4];
#pragma unroll
    for (int i = 0; i < 4; ++i) {
      af[i] = *(const bf16x8*)(As + (i * 16 + fr) * BK + fq);        // A[m=fr][k=fq..+7]
      bfm[i] = *(const bf16x8*)(Bs + (wn + i * 16 + fr) * BSTR + fq); // B[k=fq..+7][n=fr]
    }
#pragma unroll
    for (int mi = 0; mi < 4; ++mi)
#pragma unroll
      for (int ni = 0; ni < 4; ++ni)
        acc[mi][ni] =
            __builtin_amdgcn_mfma_f32_16x16x32_bf16(af[mi], bfm[ni], acc[mi][ni], 0, 0, 0);
    __syncthreads();
  }

  // C/D layout (m89-verified): col = lane&15, row = (lane>>4)*4 + reg
  const int r0 = (lane >> 4) * 4;
  const int ocol = j * BS + wn + fr;
#pragma unroll
  for (int mi = 0; mi < 4; ++mi)
#pragma unroll
    for (int ni = 0; ni < 4; ++ni) {
      float* op = out + (size_t)(m0 + mi * 16 + r0) * LDX + ocol + ni * 16;
#pragma unroll
      for (int r = 0; r < 4; ++r) op[(size_t)r * LDX] = acc[mi][ni][r];
    }
}

extern "C" void kernel_launch(void* const* d_in, const int* in_sizes, int n_in,
                              void* d_out, int out_size, void* d_ws, size_t ws_size,
                              hipStream_t stream) {
  const float* x = (const float*)d_in[0];       // 8192x4096 f32
  const float* blocks = (const float*)d_in[1];  // 4096x4096 f32
  // d_in[2] (mask) unused: block structure is static, tanh(0)=0.
  float* out = (float*)d_out;

  const size_t need = (size_t)NBLK * BS * BS * sizeof(unsigned short);  // 2 MB
  dim3 grid(128, NBLK);  // (mtile, block)
  if (d_ws != nullptr && ws_size >= need) {
    unsigned short* wsT = (unsigned short*)d_ws;
    tanh_pack<<<dim3(4, 4, NBLK), 256, 0, stream>>>(blocks, wsT);
    bdgemm<BK, false><<<grid, 256, 0, stream>>>(x, wsT, out);
  } else {
    // fallback: tanh fused into B staging; ldim 40 keeps ds_read_b128 16B-aligned
    bdgemm<40, true><<<grid, 256, 0, stream>>>(x, blocks, out);
  }
}